// Round 15
// baseline (235.809 us; speedup 1.0000x reference)
//
#include <hip/hip_runtime.h>

// ---------- types ----------
typedef __bf16 bf16x8 __attribute__((ext_vector_type(8)));
typedef float  f32x4  __attribute__((ext_vector_type(4)));
typedef float  f32x16 __attribute__((ext_vector_type(16)));
typedef unsigned short us8 __attribute__((ext_vector_type(8)));

__device__ __forceinline__ unsigned short f2bf(float f) {
  unsigned int u = __builtin_bit_cast(unsigned int, f);
  u += 0x7FFFu + ((u >> 16) & 1u);   // round-to-nearest-even
  return (unsigned short)(u >> 16);
}
__device__ __forceinline__ float sigmoid_f(float x) {
  return 1.f / (1.f + __expf(-x));
}
// NaN-safe fast tanh: 1 - 2/(e^{2x}+1)
__device__ __forceinline__ float tanh_f(float x) {
  float e = __expf(2.f * x);
  return 1.f - 2.f / (e + 1.f);
}

// ---------- cast+relayout primitive: one wave converts a 16row x 32col f32
// region to slot-major bf16 (region image: elem = s4*128 + r16*8 + e).
// Coalesced global reads, transpose via +1-padded LDS, contiguous 16B writes.
__device__ __forceinline__ void relayout_region(
    const float* __restrict__ srcRowBase, size_t rowStride,
    unsigned short* __restrict__ dst, float* __restrict__ lp, int lane) {
  {
    int r = lane >> 2, c = (lane & 3) << 3;
    const float* s = srcRowBase + (size_t)r * rowStride + c;
    f32x4 a = *(const f32x4*)(s);
    f32x4 b = *(const f32x4*)(s + 4);
#pragma unroll
    for (int j = 0; j < 4; ++j) { lp[r * 33 + c + j] = a[j]; lp[r * 33 + c + 4 + j] = b[j]; }
  }
  int s4 = lane >> 4, r16 = lane & 15;
  us8 o;
#pragma unroll
  for (int j = 0; j < 8; ++j) o[j] = f2bf(lp[r16 * 33 + s4 * 8 + j]);
  *(us8*)(dst + lane * 8) = o;
}

// ---------- ONE merged prep kernel: all relayouts in a single launch ----------
__global__ __launch_bounds__(256) void prep_all(
    const float* __restrict__ inp, const float* __restrict__ hidden,
    const float* __restrict__ w_ih, const float* __restrict__ w_hh,
    const float* __restrict__ w_out,
    unsigned short* __restrict__ inp_r, unsigned short* __restrict__ h_r,
    unsigned short* __restrict__ wih_r, unsigned short* __restrict__ whh_r,
    unsigned short* __restrict__ wout_r)
{
  __shared__ float lp[4][16 * 33];
  const int wIn = threadIdx.x >> 6, lane = threadIdx.x & 63;
  const int gw  = blockIdx.x * 4 + wIn;

  const float* src; unsigned short* dst; int K, local, isA;
  if      (gw < 2048) { src = inp;    dst = inp_r;  K = 512;  isA = 1; local = gw; }
  else if (gw < 6144) { src = hidden; dst = h_r;    K = 1024; isA = 1; local = gw - 2048; }
  else if (gw < 6912) { src = w_ih;   dst = wih_r;  K = 512;  isA = 0; local = gw - 6144; }
  else if (gw < 8448) { src = w_hh;   dst = whh_r;  K = 1024; isA = 0; local = gw - 6912; }
  else                { src = w_out;  dst = wout_r; K = 1024; isA = 1; local = gw - 8448; }
  const int nkt = K >> 5;

  if (isA) {
    int p = local / nkt, kt = local - p * nkt;
    const float* base = src + (size_t)p * 128 * K + kt * 32;
    unsigned short* d = dst + (size_t)local * 4096;
#pragma unroll
    for (int g = 0; g < 8; ++g)
      relayout_region(base + (size_t)g * 16 * K, K, d + g * 512, lp[wIn], lane);
  } else {
    int qg = local / nkt, kt = local - qg * nkt;
    int q = qg / 3, g = qg - q * 3;
    const float* base = src + ((size_t)g * 1024 + q * 64) * K + kt * 32;
    unsigned short* d = dst + (size_t)local * 2048;
#pragma unroll
    for (int rg = 0; rg < 4; ++rg)
      relayout_region(base + (size_t)rg * 16 * K, K, d + rg * 512, lp[wIn], lane);
  }
}

#define GLOAD(gp, lp) __builtin_amdgcn_global_load_lds( \
    (const __attribute__((address_space(1))) unsigned int*)(gp), \
    (__attribute__((address_space(3))) unsigned int*)(lp), 16, 0, 0)

#define MFMA32(A, B, C) __builtin_amdgcn_mfma_f32_32x32x16_bf16(A, B, C, 0, 0, 0)

// ---------- Fused GRU cell: r14 schedule + 32x32x16 MFMA shape.
// Wave tile 64x32 per gate as 2 m-positions of 32x32; 12 MFMA/step (was 24),
// 16% fewer matrix-pipe cycles, identical LDS traffic (10 ds_read_b128) and
// identical acc register count (2 x f32x16 x 4 sets = 128).
// A-frag (32x32x16): lane = row(l&31) + 32*kblock(l>>5), 8 k-elems/lane.
// In region coords: region += (l>>4)&1, k-octet = s*2 + (l>>5).
__global__ __launch_bounds__(256, 2) void fused_gru(
    const unsigned short* __restrict__ inp_r,
    const unsigned short* __restrict__ h_r,
    const unsigned short* __restrict__ wih_r,
    const unsigned short* __restrict__ whh_r,
    const float* __restrict__ b_ih,
    const float* __restrict__ b_hh,
    const float* __restrict__ hidden,      // [B,1024] f32
    float* __restrict__ hnew_f32,
    unsigned short* __restrict__ hnew_img)
{
  __shared__ unsigned short ls[4][10240];   // 4 x 20KB rotation

  const int tid  = threadIdx.x;
  const int lane = tid & 63;
  const int wave = tid >> 6;
  const int wr = wave >> 1, wc = wave & 1;

  const int f  = blockIdx.y * 16 + blockIdx.x;     // launch-order id
  const int bx = ((f & 7) << 1) | ((f >> 3) & 1);  // W-panel column 0..15
  const int by = f >> 4;                           // A row-panel 0..127

  f32x16 accR[2], accZ[2], accNi[2], accNh[2];
#pragma unroll
  for (int m = 0; m < 2; ++m) {
    accR[m]  = (f32x16)0.f;
    accZ[m]  = (f32x16)0.f;
    accNi[m] = (f32x16)0.f;
    accNh[m] = (f32x16)0.f;
  }

  // per-lane fragment read offset (elems): region-parity + k-octet + row
  const int rA2 = ((lane >> 4) & 1) * 512 + (lane >> 5) * 128 + (lane & 15) * 8;

  // induction staging pointers (wave-uniform; advance per step)
  const unsigned short* aptr = inp_r + (size_t)by * (16 * 4096);
  const unsigned short* wptr = wih_r + (size_t)bx * (3 * 16 * 2048);
  int wgs = 16 * 2048;                       // gate stride (elems)

#define STAGE(BUF) do { \
    GLOAD(aptr + tid * 8,           &ls[BUF][tid * 8]); \
    GLOAD(aptr + 2048 + tid * 8,    &ls[BUF][2048 + tid * 8]); \
    GLOAD(wptr + tid * 8,           &ls[BUF][4096 + tid * 8]); \
    GLOAD(wptr + wgs + tid * 8,     &ls[BUF][6144 + tid * 8]); \
    GLOAD(wptr + 2 * wgs + tid * 8, &ls[BUF][8192 + tid * 8]); \
    aptr += 4096; wptr += 2048; \
  } while (0)

#define COMPUTE(BUF, ACCN) do { \
    const unsigned short* lb = &ls[BUF][0]; \
    _Pragma("unroll") for (int s = 0; s < 2; ++s) { \
      bf16x8 af0 = *(const bf16x8*)&lb[(wr * 4 + 0) * 512 + s * 256 + rA2]; \
      bf16x8 af1 = *(const bf16x8*)&lb[(wr * 4 + 2) * 512 + s * 256 + rA2]; \
      bf16x8 b0  = *(const bf16x8*)&lb[4096 + 0 * 2048 + wc * 1024 + s * 256 + rA2]; \
      bf16x8 b1  = *(const bf16x8*)&lb[4096 + 1 * 2048 + wc * 1024 + s * 256 + rA2]; \
      bf16x8 b2  = *(const bf16x8*)&lb[4096 + 2 * 2048 + wc * 1024 + s * 256 + rA2]; \
      __builtin_amdgcn_s_setprio(1); \
      accR[0] = MFMA32(af0, b0, accR[0]); \
      accR[1] = MFMA32(af1, b0, accR[1]); \
      accZ[0] = MFMA32(af0, b1, accZ[0]); \
      accZ[1] = MFMA32(af1, b1, accZ[1]); \
      ACCN[0] = MFMA32(af0, b2, ACCN[0]); \
      ACCN[1] = MFMA32(af1, b2, ACCN[1]); \
      __builtin_amdgcn_s_setprio(0); \
    } \
  } while (0)

#define WAIT10 asm volatile("s_waitcnt vmcnt(10)" ::: "memory")
#define BARR   __builtin_amdgcn_s_barrier()
#define STEP(SB, CB, ACCN) do { STAGE(SB); WAIT10; BARR; COMPUTE(CB, ACCN); } while (0)

  // 48 kt32 tiles: 0..15 inp/wih -> accNi, 16..47 h/whh -> accNh
  STAGE(0); STAGE(1);                        // tiles 0,1
#pragma unroll 1
  for (int i = 0; i < 3; ++i) {              // t = 0..11, stage 2..13
    STEP(2, 0, accNi); STEP(3, 1, accNi); STEP(0, 2, accNi); STEP(1, 3, accNi);
  }
  STEP(2, 0, accNi);                         // t=12, stage 14
  STEP(3, 1, accNi);                         // t=13, stage 15
  aptr = h_r + (size_t)by * (32 * 4096);     // switch to h-phase
  wptr = whh_r + (size_t)bx * (3 * 32 * 2048);
  wgs = 32 * 2048;
  STEP(0, 2, accNi);                         // t=14, stage 16
  STEP(1, 3, accNi);                         // t=15, stage 17
#pragma unroll 1
  for (int i = 0; i < 7; ++i) {              // t = 16..43, stage 18..45
    STEP(2, 0, accNh); STEP(3, 1, accNh); STEP(0, 2, accNh); STEP(1, 3, accNh);
  }
  STEP(2, 0, accNh);                         // t=44, stage 46
  STEP(3, 1, accNh);                         // t=45, stage 47
  asm volatile("s_waitcnt vmcnt(5)" ::: "memory"); BARR;
  COMPUTE(2, accNh);                         // t=46
  asm volatile("s_waitcnt vmcnt(0)" ::: "memory"); BARR;
  COMPUTE(3, accNh);                         // t=47

#undef STAGE
#undef COMPUTE
#undef WAIT10
#undef BARR
#undef STEP

  // ---- epilogue: gate math + blend ----
  // 32x32 C/D layout [m74/m101]: col = lane&31, row = (reg&3)+8*(reg>>2)+4*(lane>>5)
  const int m0 = by * 128;
  const int n0 = bx * 64;
  const int c  = n0 + wc * 32 + (lane & 31);
  const int rbase = m0 + wr * 64 + ((lane >> 5) << 2);
  float br  = b_ih[c]        + b_hh[c];
  float bz  = b_ih[1024 + c] + b_hh[1024 + c];
  float bni = b_ih[2048 + c];
  float bnh = b_hh[2048 + c];
  const int kt = c >> 5;                 // image k-chunk
  const int sl = (c >> 3) & 3;           // k-octet slot
  const int e  = c & 7;
#pragma unroll
  for (int m = 0; m < 2; ++m) {
#pragma unroll
    for (int r = 0; r < 16; ++r) {
      int rw = rbase + m * 32 + (r & 3) + ((r >> 2) << 3);
      float rg = sigmoid_f(accR[m][r] + br);
      float zg = sigmoid_f(accZ[m][r] + bz);
      float ng = tanh_f((accNi[m][r] + bni) + rg * (accNh[m][r] + bnh));
      float ho = hidden[(size_t)rw * 1024 + c];
      float hv = (1.f - zg) * ng + zg * ho;
      hnew_f32[(size_t)rw * 1024 + c] = hv;
      // slot-major GEMM A-image: tile (p*32+kt), region (row>>4)&7
      size_t img = ((size_t)((rw >> 7) * 32 + kt)) * 4096
                 + (((rw >> 4) & 7) * 512) + sl * 128 + (rw & 15) * 8 + e;
      hnew_img[img] = f2bf(hv);
    }
  }
}

// ---------- out GEMM: r12 structure (16x16x32, unchanged). ----------
__global__ __launch_bounds__(256, 2) void gemm_out(
    const unsigned short* __restrict__ A_img,   // [128 p-tiles][32 kt][4096]
    const unsigned short* __restrict__ B_img,   // [4 p-tiles][32 kt][4096]
    float* __restrict__ Cout,
    const float* __restrict__ bias)
{
  __shared__ unsigned short ls[4][8192];   // 4 x 16KB rotation (A 4096 | B 4096)

  const int tid  = threadIdx.x;
  const int lane = tid & 63;
  const int wave = tid >> 6;
  const int wr = wave >> 1, wc = wave & 1;

  f32x4 acc[4][4];
#pragma unroll
  for (int i = 0; i < 4; ++i)
#pragma unroll
    for (int j = 0; j < 4; ++j) acc[i][j] = f32x4{0.f, 0.f, 0.f, 0.f};

  const int t4   = lane >> 4;
  const int l15  = lane & 15;
  const int rofs = t4 * 128 + l15 * 8;

  const unsigned short* aptr = A_img + (size_t)blockIdx.y * (32 * 4096);
  const unsigned short* bptr = B_img + (size_t)blockIdx.x * (32 * 4096);

#define STAGE(BUF) do { \
    GLOAD(aptr + tid * 8,        &ls[BUF][tid * 8]); \
    GLOAD(aptr + 2048 + tid * 8, &ls[BUF][2048 + tid * 8]); \
    GLOAD(bptr + tid * 8,        &ls[BUF][4096 + tid * 8]); \
    GLOAD(bptr + 2048 + tid * 8, &ls[BUF][6144 + tid * 8]); \
    aptr += 4096; bptr += 4096; \
  } while (0)

#define COMPUTE(BUF) do { \
    const unsigned short* lb = &ls[BUF][0]; \
    bf16x8 af[4], bfr[4]; \
    _Pragma("unroll") for (int m = 0; m < 4; ++m) \
      af[m] = *(const bf16x8*)&lb[(wr * 4 + m) * 512 + rofs]; \
    _Pragma("unroll") for (int n = 0; n < 4; ++n) \
      bfr[n] = *(const bf16x8*)&lb[4096 + (wc * 4 + n) * 512 + rofs]; \
    __builtin_amdgcn_s_setprio(1); \
    _Pragma("unroll") for (int m = 0; m < 4; ++m) { \
      _Pragma("unroll") for (int n = 0; n < 4; ++n) \
        acc[m][n] = __builtin_amdgcn_mfma_f32_16x16x32_bf16(af[m], bfr[n], acc[m][n], 0, 0, 0); \
    } \
    __builtin_amdgcn_s_setprio(0); \
  } while (0)

#define WAIT8 asm volatile("s_waitcnt vmcnt(8)" ::: "memory")
#define BARR  __builtin_amdgcn_s_barrier()
#define STEP(SB, CB) do { STAGE(SB); WAIT8; BARR; COMPUTE(CB); } while (0)

  STAGE(0); STAGE(1);
#pragma unroll 1
  for (int i = 0; i < 7; ++i) {              // t = 0..27, stage 2..29
    STEP(2, 0); STEP(3, 1); STEP(0, 2); STEP(1, 3);
  }
  STEP(2, 0);                                // t=28, stage 30
  STEP(3, 1);                                // t=29, stage 31
  asm volatile("s_waitcnt vmcnt(4)" ::: "memory"); BARR;
  COMPUTE(2);                                // t=30
  asm volatile("s_waitcnt vmcnt(0)" ::: "memory"); BARR;
  COMPUTE(3);                                // t=31

#undef STAGE
#undef COMPUTE
#undef WAIT8
#undef BARR
#undef STEP

  const int m0 = blockIdx.y * 128;
  const int n0 = blockIdx.x * 128;
  const int colb = n0 + wc * 64 + l15;
  const int rowb = m0 + wr * 64 + (t4 << 2);
#pragma unroll
  for (int n = 0; n < 4; ++n) {
    int col = colb + n * 16;
    float bv = bias[col];
#pragma unroll
    for (int m = 0; m < 4; ++m) {
      int row = rowb + m * 16;
#pragma unroll
      for (int r = 0; r < 4; ++r) {
        Cout[(size_t)(row + r) * 512 + col] = tanh_f(acc[m][n][r] + bv);
      }
    }
  }
}

// ---------- launch ----------
extern "C" void kernel_launch(void* const* d_in, const int* in_sizes, int n_in,
                              void* d_out, int out_size, void* d_ws, size_t ws_size,
                              hipStream_t stream) {
  const int B = 16384, H = 1024, O = 512;
  const float* inp    = (const float*)d_in[0];
  const float* hidden = (const float*)d_in[1];
  const float* w_ih   = (const float*)d_in[2];
  const float* w_hh   = (const float*)d_in[3];
  const float* b_ih   = (const float*)d_in[4];
  const float* b_hh   = (const float*)d_in[5];
  const float* w_out  = (const float*)d_in[6];
  const float* b_out  = (const float*)d_in[7];

  float* out      = (float*)d_out;                     // [B, O] f32
  float* hnew_out = out + (size_t)B * O;               // [1, B, H] f32

  char* ws = (char*)d_ws;
  size_t need = 0;
  auto carve = [&](size_t elems) {
    unsigned short* p = (unsigned short*)(ws + need);
    need += elems * 2;
    return p;
  };
  unsigned short* inp_r  = carve((size_t)B * O);       // 16 MB (image)
  unsigned short* h_r    = carve((size_t)B * H);       // 32 MB (image)
  unsigned short* wih_r  = carve((size_t)3 * H * O);   // 3 MB (image)
  unsigned short* whh_r  = carve((size_t)3 * H * H);   // 6 MB (image)
  unsigned short* wout_r = carve((size_t)O * H);       // 1 MB (image)
  unsigned short* hnew_i = carve((size_t)B * H);       // 32 MB (image)
  if (ws_size < need) return;

  // one merged prep launch: 8576 waves -> 2144 blocks
  prep_all<<<dim3(2144), dim3(256), 0, stream>>>(
      inp, hidden, w_ih, w_hh, w_out, inp_r, h_r, wih_r, whh_r, wout_r);

  // fused GRU cell -> h_new (f32 into d_out tail, bf16 image into ws)
  fused_gru<<<dim3(H / 64, B / 128), dim3(256), 0, stream>>>(
      inp_r, h_r, wih_r, whh_r, b_ih, b_hh, hidden, hnew_out, hnew_i);

  // out = tanh(h_new @ w_out^T + b_out)
  gemm_out<<<dim3(O / 128, B / 128), dim3(256), 0, stream>>>(
      hnew_i, wout_r, out, b_out);
}

// Round 16
// 226.198 us; speedup vs baseline: 1.0425x; 1.0425x over previous
//
#include <hip/hip_runtime.h>

// ---------- types ----------
typedef __bf16 bf16x8 __attribute__((ext_vector_type(8)));
typedef float  f32x4  __attribute__((ext_vector_type(4)));
typedef unsigned short us8 __attribute__((ext_vector_type(8)));

__device__ __forceinline__ unsigned short f2bf(float f) {
  unsigned int u = __builtin_bit_cast(unsigned int, f);
  u += 0x7FFFu + ((u >> 16) & 1u);   // round-to-nearest-even
  return (unsigned short)(u >> 16);
}
__device__ __forceinline__ float sigmoid_f(float x) {
  return 1.f / (1.f + __expf(-x));
}
// NaN-safe fast tanh: 1 - 2/(e^{2x}+1)
__device__ __forceinline__ float tanh_f(float x) {
  float e = __expf(2.f * x);
  return 1.f - 2.f / (e + 1.f);
}

// ---------- cast+relayout primitive: one wave converts a 16row x 32col f32
// region to slot-major bf16 (region image: elem = s4*128 + r16*8 + e).
// Coalesced global reads, transpose via +1-padded LDS, contiguous 16B writes.
__device__ __forceinline__ void relayout_region(
    const float* __restrict__ srcRowBase, size_t rowStride,
    unsigned short* __restrict__ dst, float* __restrict__ lp, int lane) {
  {
    int r = lane >> 2, c = (lane & 3) << 3;
    const float* s = srcRowBase + (size_t)r * rowStride + c;
    f32x4 a = *(const f32x4*)(s);
    f32x4 b = *(const f32x4*)(s + 4);
#pragma unroll
    for (int j = 0; j < 4; ++j) { lp[r * 33 + c + j] = a[j]; lp[r * 33 + c + 4 + j] = b[j]; }
  }
  int s4 = lane >> 4, r16 = lane & 15;
  us8 o;
#pragma unroll
  for (int j = 0; j < 8; ++j) o[j] = f2bf(lp[r16 * 33 + s4 * 8 + j]);
  *(us8*)(dst + lane * 8) = o;
}

// ---------- ONE merged prep kernel: all relayouts in a single launch ----------
__global__ __launch_bounds__(256) void prep_all(
    const float* __restrict__ inp, const float* __restrict__ hidden,
    const float* __restrict__ w_ih, const float* __restrict__ w_hh,
    const float* __restrict__ w_out,
    unsigned short* __restrict__ inp_r, unsigned short* __restrict__ h_r,
    unsigned short* __restrict__ wih_r, unsigned short* __restrict__ whh_r,
    unsigned short* __restrict__ wout_r)
{
  __shared__ float lp[4][16 * 33];
  const int wIn = threadIdx.x >> 6, lane = threadIdx.x & 63;
  const int gw  = blockIdx.x * 4 + wIn;

  const float* src; unsigned short* dst; int K, local, isA;
  if      (gw < 2048) { src = inp;    dst = inp_r;  K = 512;  isA = 1; local = gw; }
  else if (gw < 6144) { src = hidden; dst = h_r;    K = 1024; isA = 1; local = gw - 2048; }
  else if (gw < 6912) { src = w_ih;   dst = wih_r;  K = 512;  isA = 0; local = gw - 6144; }
  else if (gw < 8448) { src = w_hh;   dst = whh_r;  K = 1024; isA = 0; local = gw - 6912; }
  else                { src = w_out;  dst = wout_r; K = 1024; isA = 1; local = gw - 8448; }
  const int nkt = K >> 5;

  if (isA) {
    int p = local / nkt, kt = local - p * nkt;
    const float* base = src + (size_t)p * 128 * K + kt * 32;
    unsigned short* d = dst + (size_t)local * 4096;
#pragma unroll
    for (int g = 0; g < 8; ++g)
      relayout_region(base + (size_t)g * 16 * K, K, d + g * 512, lp[wIn], lane);
  } else {
    int qg = local / nkt, kt = local - qg * nkt;
    int q = qg / 3, g = qg - q * 3;
    const float* base = src + ((size_t)g * 1024 + q * 64) * K + kt * 32;
    unsigned short* d = dst + (size_t)local * 2048;
#pragma unroll
    for (int rg = 0; rg < 4; ++rg)
      relayout_region(base + (size_t)rg * 16 * K, K, d + rg * 512, lp[wIn], lane);
  }
}

#define GLOAD(gp, lp) __builtin_amdgcn_global_load_lds( \
    (const __attribute__((address_space(1))) unsigned int*)(gp), \
    (__attribute__((address_space(3))) unsigned int*)(lp), 16, 0, 0)

// ---------- Fused GRU cell: BK=64, 2 x 40KB double-buffer, static macro
// buffers + induction pointers (r10 discipline), 24 steps (was 48) -> per-step
// latency/sync overhead paid half as often. COMPUTE body = r14's verified
// 16x16x32 code, called for ks=0,1. Race safety: trailing barrier of step t-1
// orders all COMPUTE(B) before any STAGE(B) of step t; per-wave vmcnt(10)
// before barrier1 covers tile t's own loads; barrier publishes. ----------
__global__ __launch_bounds__(256, 2) void fused_gru(
    const unsigned short* __restrict__ inp_r,
    const unsigned short* __restrict__ h_r,
    const unsigned short* __restrict__ wih_r,
    const unsigned short* __restrict__ whh_r,
    const float* __restrict__ b_ih,
    const float* __restrict__ b_hh,
    const float* __restrict__ hidden,      // [B,1024] f32
    float* __restrict__ hnew_f32,
    unsigned short* __restrict__ hnew_img)
{
  __shared__ unsigned short ls[2][20480];   // 2 x 40KB (one BK=64 tile each)

  const int tid  = threadIdx.x;
  const int lane = tid & 63;
  const int wave = tid >> 6;
  const int wr = wave >> 1, wc = wave & 1;

  const int f  = blockIdx.y * 16 + blockIdx.x;     // launch-order id
  const int bx = ((f & 7) << 1) | ((f >> 3) & 1);  // W-panel column 0..15
  const int by = f >> 4;                           // A row-panel 0..127

  f32x4 accR[4][2], accZ[4][2], accNi[4][2], accNh[4][2];
#pragma unroll
  for (int m = 0; m < 4; ++m)
#pragma unroll
    for (int n = 0; n < 2; ++n) {
      accR[m][n]  = f32x4{0.f, 0.f, 0.f, 0.f};
      accZ[m][n]  = f32x4{0.f, 0.f, 0.f, 0.f};
      accNi[m][n] = f32x4{0.f, 0.f, 0.f, 0.f};
      accNh[m][n] = f32x4{0.f, 0.f, 0.f, 0.f};
    }

  const int t4   = lane >> 4;                // k-octet 0..3
  const int l15  = lane & 15;
  const int rofs = t4 * 128 + l15 * 8;       // within-region read offset (elems)

  // induction staging pointers (wave-uniform; advance per BK=64 step)
  const unsigned short* aptr = inp_r + (size_t)by * (16 * 4096);
  const unsigned short* w0   = wih_r + (size_t)bx * (3 * 16 * 2048);
  const unsigned short* w1   = w0 + 16 * 2048;
  const unsigned short* w2   = w1 + 16 * 2048;

  // buffer layout (elems): [A img0 0..4095][A img1 4096..8191]
  //                        [g0 img0 @8192][g0 img1 @10240][g1 @12288/14336][g2 @16384/18432]
#define STAGE(BUF) do { \
    GLOAD(aptr + tid * 8,        &ls[BUF][tid * 8]); \
    GLOAD(aptr + 2048 + tid * 8, &ls[BUF][2048 + tid * 8]); \
    GLOAD(aptr + 4096 + tid * 8, &ls[BUF][4096 + tid * 8]); \
    GLOAD(aptr + 6144 + tid * 8, &ls[BUF][6144 + tid * 8]); \
    GLOAD(w0 + tid * 8,          &ls[BUF][8192 + tid * 8]); \
    GLOAD(w0 + 2048 + tid * 8,   &ls[BUF][10240 + tid * 8]); \
    GLOAD(w1 + tid * 8,          &ls[BUF][12288 + tid * 8]); \
    GLOAD(w1 + 2048 + tid * 8,   &ls[BUF][14336 + tid * 8]); \
    GLOAD(w2 + tid * 8,          &ls[BUF][16384 + tid * 8]); \
    GLOAD(w2 + 2048 + tid * 8,   &ls[BUF][18432 + tid * 8]); \
    aptr += 8192; w0 += 4096; w1 += 4096; w2 += 4096; \
  } while (0)

#define COMPUTE(BUF, KS, ACCN) do { \
    const unsigned short* la = &ls[BUF][(KS) * 4096]; \
    const unsigned short* lw = &ls[BUF][8192 + (KS) * 2048]; \
    bf16x8 af[4], bfr[3][2]; \
    _Pragma("unroll") for (int m = 0; m < 4; ++m) \
      af[m] = *(const bf16x8*)&la[(wr * 4 + m) * 512 + rofs]; \
    _Pragma("unroll") for (int g = 0; g < 3; ++g) { \
      _Pragma("unroll") for (int n = 0; n < 2; ++n) \
        bfr[g][n] = *(const bf16x8*)&lw[g * 4096 + (wc * 2 + n) * 512 + rofs]; \
    } \
    __builtin_amdgcn_s_setprio(1); \
    _Pragma("unroll") for (int m = 0; m < 4; ++m) { \
      _Pragma("unroll") for (int n = 0; n < 2; ++n) { \
        accR[m][n] = __builtin_amdgcn_mfma_f32_16x16x32_bf16(af[m], bfr[0][n], accR[m][n], 0, 0, 0); \
        accZ[m][n] = __builtin_amdgcn_mfma_f32_16x16x32_bf16(af[m], bfr[1][n], accZ[m][n], 0, 0, 0); \
        ACCN[m][n] = __builtin_amdgcn_mfma_f32_16x16x32_bf16(af[m], bfr[2][n], ACCN[m][n], 0, 0, 0); \
      } \
    } \
    __builtin_amdgcn_s_setprio(0); \
  } while (0)

#define WAIT10 asm volatile("s_waitcnt vmcnt(10)" ::: "memory")
#define WAIT0  asm volatile("s_waitcnt vmcnt(0)" ::: "memory")
#define BARR   __builtin_amdgcn_s_barrier()
#define STEP(SB, CB, ACCN) do { STAGE(SB); WAIT10; BARR; \
    COMPUTE(CB, 0, ACCN); COMPUTE(CB, 1, ACCN); BARR; } while (0)

  // 24 BK=64 tiles: 0..7 = inp/wih -> accNi, 8..23 = h/whh -> accNh
  STAGE(0);                                  // tile 0
#pragma unroll 1
  for (int i = 0; i < 3; ++i) {              // t = 0..5, stage tiles 1..6
    STEP(1, 0, accNi); STEP(0, 1, accNi);
  }
  STEP(1, 0, accNi);                         // t=6, stage tile 7 (inp)
  // switch to h-phase (next stage = tile 8)
  aptr = h_r + (size_t)by * (32 * 4096);
  w0 = whh_r + (size_t)bx * (3 * 32 * 2048);
  w1 = w0 + 32 * 2048;
  w2 = w1 + 32 * 2048;
  STEP(0, 1, accNi);                         // t=7, stage tile 8 (h)
#pragma unroll 1
  for (int i = 0; i < 7; ++i) {              // t = 8..21, stage tiles 9..22
    STEP(1, 0, accNh); STEP(0, 1, accNh);
  }
  STEP(1, 0, accNh);                         // t=22, stage tile 23
  WAIT0; BARR;                               // t=23 (no stage)
  COMPUTE(1, 0, accNh); COMPUTE(1, 1, accNh);

#undef STAGE
#undef COMPUTE
#undef WAIT10
#undef WAIT0
#undef BARR
#undef STEP

  // ---- epilogue: gate math + blend ----
  // C/D layout: col = lane&15, row = (lane>>4)*4 + r
  const int m0 = by * 128;
  const int n0 = bx * 64;
  const int colb = n0 + wc * 32 + l15;
  const int rowb = m0 + wr * 64 + (t4 << 2);
#pragma unroll
  for (int n = 0; n < 2; ++n) {
    int c = colb + n * 16;
    float br  = b_ih[c]        + b_hh[c];
    float bz  = b_ih[1024 + c] + b_hh[1024 + c];
    float bni = b_ih[2048 + c];
    float bnh = b_hh[2048 + c];
    const int kt = c >> 5;                 // image k-chunk
    const int s  = (c >> 3) & 3;           // k-octet slot
    const int e  = c & 7;
#pragma unroll
    for (int m = 0; m < 4; ++m) {
      int row = rowb + m * 16;
#pragma unroll
      for (int r = 0; r < 4; ++r) {
        float rg = sigmoid_f(accR[m][n][r] + br);
        float zg = sigmoid_f(accZ[m][n][r] + bz);
        float ng = tanh_f((accNi[m][n][r] + bni) + rg * (accNh[m][n][r] + bnh));
        int rw = row + r;
        float ho = hidden[(size_t)rw * 1024 + c];
        float hv = (1.f - zg) * ng + zg * ho;
        hnew_f32[(size_t)rw * 1024 + c] = hv;
        // slot-major GEMM A-image: tile (p*32+kt), region (row>>4)&7
        size_t img = ((size_t)((rw >> 7) * 32 + kt)) * 4096
                   + (((rw >> 4) & 7) * 512) + s * 128 + (rw & 15) * 8 + e;
        hnew_img[img] = f2bf(hv);
      }
    }
  }
}

// ---------- out GEMM: r12 structure (16x16x32, 4-buffer rotation). ----------
__global__ __launch_bounds__(256, 2) void gemm_out(
    const unsigned short* __restrict__ A_img,   // [128 p-tiles][32 kt][4096]
    const unsigned short* __restrict__ B_img,   // [4 p-tiles][32 kt][4096]
    float* __restrict__ Cout,
    const float* __restrict__ bias)
{
  __shared__ unsigned short ls[4][8192];   // 4 x 16KB rotation (A 4096 | B 4096)

  const int tid  = threadIdx.x;
  const int lane = tid & 63;
  const int wave = tid >> 6;
  const int wr = wave >> 1, wc = wave & 1;

  f32x4 acc[4][4];
#pragma unroll
  for (int i = 0; i < 4; ++i)
#pragma unroll
    for (int j = 0; j < 4; ++j) acc[i][j] = f32x4{0.f, 0.f, 0.f, 0.f};

  const int t4   = lane >> 4;
  const int l15  = lane & 15;
  const int rofs = t4 * 128 + l15 * 8;

  const unsigned short* aptr = A_img + (size_t)blockIdx.y * (32 * 4096);
  const unsigned short* bptr = B_img + (size_t)blockIdx.x * (32 * 4096);

#define STAGE(BUF) do { \
    GLOAD(aptr + tid * 8,        &ls[BUF][tid * 8]); \
    GLOAD(aptr + 2048 + tid * 8, &ls[BUF][2048 + tid * 8]); \
    GLOAD(bptr + tid * 8,        &ls[BUF][4096 + tid * 8]); \
    GLOAD(bptr + 2048 + tid * 8, &ls[BUF][6144 + tid * 8]); \
    aptr += 4096; bptr += 4096; \
  } while (0)

#define COMPUTE(BUF) do { \
    const unsigned short* lb = &ls[BUF][0]; \
    bf16x8 af[4], bfr[4]; \
    _Pragma("unroll") for (int m = 0; m < 4; ++m) \
      af[m] = *(const bf16x8*)&lb[(wr * 4 + m) * 512 + rofs]; \
    _Pragma("unroll") for (int n = 0; n < 4; ++n) \
      bfr[n] = *(const bf16x8*)&lb[4096 + (wc * 4 + n) * 512 + rofs]; \
    __builtin_amdgcn_s_setprio(1); \
    _Pragma("unroll") for (int m = 0; m < 4; ++m) { \
      _Pragma("unroll") for (int n = 0; n < 4; ++n) \
        acc[m][n] = __builtin_amdgcn_mfma_f32_16x16x32_bf16(af[m], bfr[n], acc[m][n], 0, 0, 0); \
    } \
    __builtin_amdgcn_s_setprio(0); \
  } while (0)

#define WAIT8 asm volatile("s_waitcnt vmcnt(8)" ::: "memory")
#define BARR  __builtin_amdgcn_s_barrier()
#define STEP(SB, CB) do { STAGE(SB); WAIT8; BARR; COMPUTE(CB); } while (0)

  STAGE(0); STAGE(1);
#pragma unroll 1
  for (int i = 0; i < 7; ++i) {              // t = 0..27, stage 2..29
    STEP(2, 0); STEP(3, 1); STEP(0, 2); STEP(1, 3);
  }
  STEP(2, 0);                                // t=28, stage 30
  STEP(3, 1);                                // t=29, stage 31
  asm volatile("s_waitcnt vmcnt(4)" ::: "memory"); BARR;
  COMPUTE(2);                                // t=30
  asm volatile("s_waitcnt vmcnt(0)" ::: "memory"); BARR;
  COMPUTE(3);                                // t=31

#undef STAGE
#undef COMPUTE
#undef WAIT8
#undef BARR
#undef STEP

  const int m0 = blockIdx.y * 128;
  const int n0 = blockIdx.x * 128;
  const int colb = n0 + wc * 64 + l15;
  const int rowb = m0 + wr * 64 + (t4 << 2);
#pragma unroll
  for (int n = 0; n < 4; ++n) {
    int col = colb + n * 16;
    float bv = bias[col];
#pragma unroll
    for (int m = 0; m < 4; ++m) {
      int row = rowb + m * 16;
#pragma unroll
      for (int r = 0; r < 4; ++r) {
        Cout[(size_t)(row + r) * 512 + col] = tanh_f(acc[m][n][r] + bv);
      }
    }
  }
}

// ---------- launch ----------
extern "C" void kernel_launch(void* const* d_in, const int* in_sizes, int n_in,
                              void* d_out, int out_size, void* d_ws, size_t ws_size,
                              hipStream_t stream) {
  const int B = 16384, H = 1024, O = 512;
  const float* inp    = (const float*)d_in[0];
  const float* hidden = (const float*)d_in[1];
  const float* w_ih   = (const float*)d_in[2];
  const float* w_hh   = (const float*)d_in[3];
  const float* b_ih   = (const float*)d_in[4];
  const float* b_hh   = (const float*)d_in[5];
  const float* w_out  = (const float*)d_in[6];
  const float* b_out  = (const float*)d_in[7];

  float* out      = (float*)d_out;                     // [B, O] f32
  float* hnew_out = out + (size_t)B * O;               // [1, B, H] f32

  char* ws = (char*)d_ws;
  size_t need = 0;
  auto carve = [&](size_t elems) {
    unsigned short* p = (unsigned short*)(ws + need);
    need += elems * 2;
    return p;
  };
  unsigned short* inp_r  = carve((size_t)B * O);       // 16 MB (image)
  unsigned short* h_r    = carve((size_t)B * H);       // 32 MB (image)
  unsigned short* wih_r  = carve((size_t)3 * H * O);   // 3 MB (image)
  unsigned short* whh_r  = carve((size_t)3 * H * H);   // 6 MB (image)
  unsigned short* wout_r = carve((size_t)O * H);       // 1 MB (image)
  unsigned short* hnew_i = carve((size_t)B * H);       // 32 MB (image)
  if (ws_size < need) return;

  // one merged prep launch: 8576 waves -> 2144 blocks
  prep_all<<<dim3(2144), dim3(256), 0, stream>>>(
      inp, hidden, w_ih, w_hh, w_out, inp_r, h_r, wih_r, whh_r, wout_r);

  // fused GRU cell -> h_new (f32 into d_out tail, bf16 image into ws)
  fused_gru<<<dim3(H / 64, B / 128), dim3(256), 0, stream>>>(
      inp_r, h_r, wih_r, whh_r, b_ih, b_hh, hidden, hnew_out, hnew_i);

  // out = tanh(h_new @ w_out^T + b_out)
  gemm_out<<<dim3(O / 128, B / 128), dim3(256), 0, stream>>>(
      hnew_i, wout_r, out, b_out);
}

// Round 17
// 221.937 us; speedup vs baseline: 1.0625x; 1.0192x over previous
//
#include <hip/hip_runtime.h>

// ---------- types ----------
typedef __bf16 bf16x8 __attribute__((ext_vector_type(8)));
typedef float  f32x4  __attribute__((ext_vector_type(4)));
typedef unsigned short us8 __attribute__((ext_vector_type(8)));

__device__ __forceinline__ unsigned short f2bf(float f) {
  unsigned int u = __builtin_bit_cast(unsigned int, f);
  u += 0x7FFFu + ((u >> 16) & 1u);   // round-to-nearest-even
  return (unsigned short)(u >> 16);
}
__device__ __forceinline__ float sigmoid_f(float x) {
  return 1.f / (1.f + __expf(-x));
}
// NaN-safe fast tanh: 1 - 2/(e^{2x}+1)
__device__ __forceinline__ float tanh_f(float x) {
  float e = __expf(2.f * x);
  return 1.f - 2.f / (e + 1.f);
}

// ---------- cast+relayout primitive: one wave converts a 16row x 32col f32
// region to slot-major bf16 (region image: elem = s4*128 + r16*8 + e).
// Coalesced global reads, transpose via +1-padded LDS, contiguous 16B writes.
__device__ __forceinline__ void relayout_region(
    const float* __restrict__ srcRowBase, size_t rowStride,
    unsigned short* __restrict__ dst, float* __restrict__ lp, int lane) {
  {
    int r = lane >> 2, c = (lane & 3) << 3;
    const float* s = srcRowBase + (size_t)r * rowStride + c;
    f32x4 a = *(const f32x4*)(s);
    f32x4 b = *(const f32x4*)(s + 4);
#pragma unroll
    for (int j = 0; j < 4; ++j) { lp[r * 33 + c + j] = a[j]; lp[r * 33 + c + 4 + j] = b[j]; }
  }
  int s4 = lane >> 4, r16 = lane & 15;
  us8 o;
#pragma unroll
  for (int j = 0; j < 8; ++j) o[j] = f2bf(lp[r16 * 33 + s4 * 8 + j]);
  *(us8*)(dst + lane * 8) = o;
}

// ---------- ONE merged prep kernel: all relayouts in a single launch ----------
__global__ __launch_bounds__(256) void prep_all(
    const float* __restrict__ inp, const float* __restrict__ hidden,
    const float* __restrict__ w_ih, const float* __restrict__ w_hh,
    const float* __restrict__ w_out,
    unsigned short* __restrict__ inp_r, unsigned short* __restrict__ h_r,
    unsigned short* __restrict__ wih_r, unsigned short* __restrict__ whh_r,
    unsigned short* __restrict__ wout_r)
{
  __shared__ float lp[4][16 * 33];
  const int wIn = threadIdx.x >> 6, lane = threadIdx.x & 63;
  const int gw  = blockIdx.x * 4 + wIn;

  const float* src; unsigned short* dst; int K, local, isA;
  if      (gw < 2048) { src = inp;    dst = inp_r;  K = 512;  isA = 1; local = gw; }
  else if (gw < 6144) { src = hidden; dst = h_r;    K = 1024; isA = 1; local = gw - 2048; }
  else if (gw < 6912) { src = w_ih;   dst = wih_r;  K = 512;  isA = 0; local = gw - 6144; }
  else if (gw < 8448) { src = w_hh;   dst = whh_r;  K = 1024; isA = 0; local = gw - 6912; }
  else                { src = w_out;  dst = wout_r; K = 1024; isA = 1; local = gw - 8448; }
  const int nkt = K >> 5;

  if (isA) {
    int p = local / nkt, kt = local - p * nkt;
    const float* base = src + (size_t)p * 128 * K + kt * 32;
    unsigned short* d = dst + (size_t)local * 4096;
#pragma unroll
    for (int g = 0; g < 8; ++g)
      relayout_region(base + (size_t)g * 16 * K, K, d + g * 512, lp[wIn], lane);
  } else {
    int qg = local / nkt, kt = local - qg * nkt;
    int q = qg / 3, g = qg - q * 3;
    const float* base = src + ((size_t)g * 1024 + q * 64) * K + kt * 32;
    unsigned short* d = dst + (size_t)local * 2048;
#pragma unroll
    for (int rg = 0; rg < 4; ++rg)
      relayout_region(base + (size_t)rg * 16 * K, K, d + rg * 512, lp[wIn], lane);
  }
}

#define GLOAD(gp, lp) __builtin_amdgcn_global_load_lds( \
    (const __attribute__((address_space(1))) unsigned int*)(gp), \
    (__attribute__((address_space(3))) unsigned int*)(lp), 16, 0, 0)

// ---------- Fused GRU cell: r14 schedule (4-buffer rotation, depth-2
// prefetch, 1 barrier/step) + epilogue store-through-LDS: after the K-loop
// the 80KB ls is dead; gate outputs land in LDS ([128][68] f32 tile + 16KB
// bf16 img tile = 2 full img tiles), then copy out in full-line runs —
// kills L2 write-allocate RMW fetches on both hnew outputs. ----------
__global__ __launch_bounds__(256, 2) void fused_gru(
    const unsigned short* __restrict__ inp_r,
    const unsigned short* __restrict__ h_r,
    const unsigned short* __restrict__ wih_r,
    const unsigned short* __restrict__ whh_r,
    const float* __restrict__ b_ih,
    const float* __restrict__ b_hh,
    const float* __restrict__ hidden,      // [B,1024] f32
    float* __restrict__ hnew_f32,
    unsigned short* __restrict__ hnew_img)
{
  __shared__ unsigned short ls[4][10240];   // 4 x 20KB rotation

  const int tid  = threadIdx.x;
  const int lane = tid & 63;
  const int wave = tid >> 6;
  const int wr = wave >> 1, wc = wave & 1;

  const int f  = blockIdx.y * 16 + blockIdx.x;     // launch-order id
  const int bx = ((f & 7) << 1) | ((f >> 3) & 1);  // W-panel column 0..15
  const int by = f >> 4;                           // A row-panel 0..127

  f32x4 accR[4][2], accZ[4][2], accNi[4][2], accNh[4][2];
#pragma unroll
  for (int m = 0; m < 4; ++m)
#pragma unroll
    for (int n = 0; n < 2; ++n) {
      accR[m][n]  = f32x4{0.f, 0.f, 0.f, 0.f};
      accZ[m][n]  = f32x4{0.f, 0.f, 0.f, 0.f};
      accNi[m][n] = f32x4{0.f, 0.f, 0.f, 0.f};
      accNh[m][n] = f32x4{0.f, 0.f, 0.f, 0.f};
    }

  const int t4   = lane >> 4;                // k-octet 0..3
  const int l15  = lane & 15;
  const int rofs = t4 * 128 + l15 * 8;       // within-region read offset (elems)

  // induction staging pointers (wave-uniform; advance per step)
  const unsigned short* aptr = inp_r + (size_t)by * (16 * 4096);
  const unsigned short* wptr = wih_r + (size_t)bx * (3 * 16 * 2048);
  int wgs = 16 * 2048;                       // gate stride (elems)

#define STAGE(BUF) do { \
    GLOAD(aptr + tid * 8,           &ls[BUF][tid * 8]); \
    GLOAD(aptr + 2048 + tid * 8,    &ls[BUF][2048 + tid * 8]); \
    GLOAD(wptr + tid * 8,           &ls[BUF][4096 + tid * 8]); \
    GLOAD(wptr + wgs + tid * 8,     &ls[BUF][6144 + tid * 8]); \
    GLOAD(wptr + 2 * wgs + tid * 8, &ls[BUF][8192 + tid * 8]); \
    aptr += 4096; wptr += 2048; \
  } while (0)

#define COMPUTE(BUF, ACCN) do { \
    const unsigned short* lb = &ls[BUF][0]; \
    bf16x8 af[4], bfr[3][2]; \
    _Pragma("unroll") for (int m = 0; m < 4; ++m) \
      af[m] = *(const bf16x8*)&lb[(wr * 4 + m) * 512 + rofs]; \
    _Pragma("unroll") for (int g = 0; g < 3; ++g) { \
      _Pragma("unroll") for (int n = 0; n < 2; ++n) \
        bfr[g][n] = *(const bf16x8*)&lb[4096 + g * 2048 + (wc * 2 + n) * 512 + rofs]; \
    } \
    __builtin_amdgcn_s_setprio(1); \
    _Pragma("unroll") for (int m = 0; m < 4; ++m) { \
      _Pragma("unroll") for (int n = 0; n < 2; ++n) { \
        accR[m][n] = __builtin_amdgcn_mfma_f32_16x16x32_bf16(af[m], bfr[0][n], accR[m][n], 0, 0, 0); \
        accZ[m][n] = __builtin_amdgcn_mfma_f32_16x16x32_bf16(af[m], bfr[1][n], accZ[m][n], 0, 0, 0); \
        ACCN[m][n] = __builtin_amdgcn_mfma_f32_16x16x32_bf16(af[m], bfr[2][n], ACCN[m][n], 0, 0, 0); \
      } \
    } \
    __builtin_amdgcn_s_setprio(0); \
  } while (0)

#define WAIT10 asm volatile("s_waitcnt vmcnt(10)" ::: "memory")
#define BARR   __builtin_amdgcn_s_barrier()
#define STEP(SB, CB, ACCN) do { STAGE(SB); WAIT10; BARR; COMPUTE(CB, ACCN); } while (0)

  // 48 kt32 tiles: 0..15 inp/wih -> accNi, 16..47 h/whh -> accNh
  STAGE(0); STAGE(1);                        // tiles 0,1
#pragma unroll 1
  for (int i = 0; i < 3; ++i) {              // t = 0..11, stage 2..13
    STEP(2, 0, accNi); STEP(3, 1, accNi); STEP(0, 2, accNi); STEP(1, 3, accNi);
  }
  STEP(2, 0, accNi);                         // t=12, stage 14
  STEP(3, 1, accNi);                         // t=13, stage 15
  aptr = h_r + (size_t)by * (32 * 4096);     // switch to h-phase
  wptr = whh_r + (size_t)bx * (3 * 32 * 2048);
  wgs = 32 * 2048;
  STEP(0, 2, accNi);                         // t=14, stage 16
  STEP(1, 3, accNi);                         // t=15, stage 17
#pragma unroll 1
  for (int i = 0; i < 7; ++i) {              // t = 16..43, stage 18..45
    STEP(2, 0, accNh); STEP(3, 1, accNh); STEP(0, 2, accNh); STEP(1, 3, accNh);
  }
  STEP(2, 0, accNh);                         // t=44, stage 46
  STEP(3, 1, accNh);                         // t=45, stage 47
  asm volatile("s_waitcnt vmcnt(5)" ::: "memory"); BARR;
  COMPUTE(2, accNh);                         // t=46
  asm volatile("s_waitcnt vmcnt(0)" ::: "memory"); BARR;
  COMPUTE(3, accNh);                         // t=47

#undef STAGE
#undef COMPUTE
#undef WAIT10
#undef BARR
#undef STEP

  // ---- epilogue: gate math -> LDS staging -> full-line global writes ----
  // LDS reuse: lsf = [128][68] f32 (34816 B, bytes 0..34815);
  //            lsi = 8192 bf16 (16 KB, bytes 34816..51199) = 2 img tiles.
  // Safe: all waves passed the final barriers; lsf/lsi don't overlap ls[3]
  // (bytes 61440+), which this wave's last COMPUTE already consumed.
  float* lsf = (float*)&ls[0][0];
  unsigned short* lsi = &ls[0][0] + 17408;

  {
    // C/D layout: col = lane&15, row = (lane>>4)*4 + r (block-local coords)
    const int colb = wc * 32 + l15;          // block-local col 0..63
    const int rowb = wr * 64 + (t4 << 2);    // block-local row
#pragma unroll
    for (int n = 0; n < 2; ++n) {
      int c  = colb + n * 16;                // block-local col
      int cg = bx * 64 + c;                  // global col
      float br  = b_ih[cg]        + b_hh[cg];
      float bz  = b_ih[1024 + cg] + b_hh[1024 + cg];
      float bni = b_ih[2048 + cg];
      float bnh = b_hh[2048 + cg];
      const int ktl = c >> 5;                // local img tile 0/1
      const int s   = (c >> 3) & 3;          // k-octet slot
      const int e   = c & 7;
#pragma unroll
      for (int m = 0; m < 4; ++m) {
        int row = rowb + m * 16;
#pragma unroll
        for (int r = 0; r < 4; ++r) {
          int rl = row + r;                  // block-local row 0..127
          float rg = sigmoid_f(accR[m][n][r] + br);
          float zg = sigmoid_f(accZ[m][n][r] + bz);
          float ng = tanh_f((accNi[m][n][r] + bni) + rg * (accNh[m][n][r] + bnh));
          float ho = hidden[(size_t)(by * 128 + rl) * 1024 + cg];
          float hv = (1.f - zg) * ng + zg * ho;
          lsf[rl * 68 + c] = hv;
          lsi[ktl * 4096 + ((rl >> 4) & 7) * 512 + s * 128 + (rl & 15) * 8 + e] = f2bf(hv);
        }
      }
    }
  }
  __builtin_amdgcn_s_barrier();

  // copy-out f32: 128 rows x 64 cols; 8 f32x4 chunks/thread, 256B runs/row
  {
    float* gbase = hnew_f32 + (size_t)(by * 128) * 1024 + bx * 64;
#pragma unroll
    for (int it = 0; it < 8; ++it) {
      int q   = it * 256 + tid;              // 0..2047
      int row = q >> 4;
      int cg4 = (q & 15) << 2;
      f32x4 v = *(const f32x4*)&lsf[row * 68 + cg4];
      *(f32x4*)(gbase + (size_t)row * 1024 + cg4) = v;
    }
  }
  // copy-out img: 2 contiguous 8KB tiles; 4 us8 chunks/thread
  {
    unsigned short* gbase = hnew_img + (size_t)(by * 32 + bx * 2) * 4096;
#pragma unroll
    for (int it = 0; it < 4; ++it) {
      int q = it * 256 + tid;                // 0..1023
      us8 v = *(const us8*)&lsi[q * 8];
      *(us8*)(gbase + q * 8) = v;
    }
  }
}

// ---------- out GEMM: r12 structure (16x16x32, 4-buffer rotation). ----------
__global__ __launch_bounds__(256, 2) void gemm_out(
    const unsigned short* __restrict__ A_img,   // [128 p-tiles][32 kt][4096]
    const unsigned short* __restrict__ B_img,   // [4 p-tiles][32 kt][4096]
    float* __restrict__ Cout,
    const float* __restrict__ bias)
{
  __shared__ unsigned short ls[4][8192];   // 4 x 16KB rotation (A 4096 | B 4096)

  const int tid  = threadIdx.x;
  const int lane = tid & 63;
  const int wave = tid >> 6;
  const int wr = wave >> 1, wc = wave & 1;

  f32x4 acc[4][4];
#pragma unroll
  for (int i = 0; i < 4; ++i)
#pragma unroll
    for (int j = 0; j < 4; ++j) acc[i][j] = f32x4{0.f, 0.f, 0.f, 0.f};

  const int t4   = lane >> 4;
  const int l15  = lane & 15;
  const int rofs = t4 * 128 + l15 * 8;

  const unsigned short* aptr = A_img + (size_t)blockIdx.y * (32 * 4096);
  const unsigned short* bptr = B_img + (size_t)blockIdx.x * (32 * 4096);

#define STAGE(BUF) do { \
    GLOAD(aptr + tid * 8,        &ls[BUF][tid * 8]); \
    GLOAD(aptr + 2048 + tid * 8, &ls[BUF][2048 + tid * 8]); \
    GLOAD(bptr + tid * 8,        &ls[BUF][4096 + tid * 8]); \
    GLOAD(bptr + 2048 + tid * 8, &ls[BUF][6144 + tid * 8]); \
    aptr += 4096; bptr += 4096; \
  } while (0)

#define COMPUTE(BUF) do { \
    const unsigned short* lb = &ls[BUF][0]; \
    bf16x8 af[4], bfr[4]; \
    _Pragma("unroll") for (int m = 0; m < 4; ++m) \
      af[m] = *(const bf16x8*)&lb[(wr * 4 + m) * 512 + rofs]; \
    _Pragma("unroll") for (int n = 0; n < 4; ++n) \
      bfr[n] = *(const bf16x8*)&lb[4096 + (wc * 4 + n) * 512 + rofs]; \
    __builtin_amdgcn_s_setprio(1); \
    _Pragma("unroll") for (int m = 0; m < 4; ++m) { \
      _Pragma("unroll") for (int n = 0; n < 4; ++n) \
        acc[m][n] = __builtin_amdgcn_mfma_f32_16x16x32_bf16(af[m], bfr[n], acc[m][n], 0, 0, 0); \
    } \
    __builtin_amdgcn_s_setprio(0); \
  } while (0)

#define WAIT8 asm volatile("s_waitcnt vmcnt(8)" ::: "memory")
#define BARR  __builtin_amdgcn_s_barrier()
#define STEP(SB, CB) do { STAGE(SB); WAIT8; BARR; COMPUTE(CB); } while (0)

  STAGE(0); STAGE(1);
#pragma unroll 1
  for (int i = 0; i < 7; ++i) {              // t = 0..27, stage 2..29
    STEP(2, 0); STEP(3, 1); STEP(0, 2); STEP(1, 3);
  }
  STEP(2, 0);                                // t=28, stage 30
  STEP(3, 1);                                // t=29, stage 31
  asm volatile("s_waitcnt vmcnt(4)" ::: "memory"); BARR;
  COMPUTE(2);                                // t=30
  asm volatile("s_waitcnt vmcnt(0)" ::: "memory"); BARR;
  COMPUTE(3);                                // t=31

#undef STAGE
#undef COMPUTE
#undef WAIT8
#undef BARR
#undef STEP

  const int m0 = blockIdx.y * 128;
  const int n0 = blockIdx.x * 128;
  const int colb = n0 + wc * 64 + l15;
  const int rowb = m0 + wr * 64 + (t4 << 2);
#pragma unroll
  for (int n = 0; n < 4; ++n) {
    int col = colb + n * 16;
    float bv = bias[col];
#pragma unroll
    for (int m = 0; m < 4; ++m) {
      int row = rowb + m * 16;
#pragma unroll
      for (int r = 0; r < 4; ++r) {
        Cout[(size_t)(row + r) * 512 + col] = tanh_f(acc[m][n][r] + bv);
      }
    }
  }
}

// ---------- launch ----------
extern "C" void kernel_launch(void* const* d_in, const int* in_sizes, int n_in,
                              void* d_out, int out_size, void* d_ws, size_t ws_size,
                              hipStream_t stream) {
  const int B = 16384, H = 1024, O = 512;
  const float* inp    = (const float*)d_in[0];
  const float* hidden = (const float*)d_in[1];
  const float* w_ih   = (const float*)d_in[2];
  const float* w_hh   = (const float*)d_in[3];
  const float* b_ih   = (const float*)d_in[4];
  const float* b_hh   = (const float*)d_in[5];
  const float* w_out  = (const float*)d_in[6];
  const float* b_out  = (const float*)d_in[7];

  float* out      = (float*)d_out;                     // [B, O] f32
  float* hnew_out = out + (size_t)B * O;               // [1, B, H] f32

  char* ws = (char*)d_ws;
  size_t need = 0;
  auto carve = [&](size_t elems) {
    unsigned short* p = (unsigned short*)(ws + need);
    need += elems * 2;
    return p;
  };
  unsigned short* inp_r  = carve((size_t)B * O);       // 16 MB (image)
  unsigned short* h_r    = carve((size_t)B * H);       // 32 MB (image)
  unsigned short* wih_r  = carve((size_t)3 * H * O);   // 3 MB (image)
  unsigned short* whh_r  = carve((size_t)3 * H * H);   // 6 MB (image)
  unsigned short* wout_r = carve((size_t)O * H);       // 1 MB (image)
  unsigned short* hnew_i = carve((size_t)B * H);       // 32 MB (image)
  if (ws_size < need) return;

  // one merged prep launch: 8576 waves -> 2144 blocks
  prep_all<<<dim3(2144), dim3(256), 0, stream>>>(
      inp, hidden, w_ih, w_hh, w_out, inp_r, h_r, wih_r, whh_r, wout_r);

  // fused GRU cell -> h_new (f32 into d_out tail, bf16 image into ws)
  fused_gru<<<dim3(16, 128), dim3(256), 0, stream>>>(
      inp_r, h_r, wih_r, whh_r, b_ih, b_hh, hidden, hnew_out, hnew_i);

  // out = tanh(h_new @ w_out^T + b_out)
  gemm_out<<<dim3(O / 128, B / 128), dim3(256), 0, stream>>>(
      hnew_i, wout_r, out, b_out);
}

// Round 18
// 218.716 us; speedup vs baseline: 1.0781x; 1.0147x over previous
//
#include <hip/hip_runtime.h>

// ---------- types ----------
typedef __bf16 bf16x8 __attribute__((ext_vector_type(8)));
typedef float  f32x4  __attribute__((ext_vector_type(4)));
typedef unsigned short us8 __attribute__((ext_vector_type(8)));

__device__ __forceinline__ unsigned short f2bf(float f) {
  unsigned int u = __builtin_bit_cast(unsigned int, f);
  u += 0x7FFFu + ((u >> 16) & 1u);   // round-to-nearest-even
  return (unsigned short)(u >> 16);
}
__device__ __forceinline__ float sigmoid_f(float x) {
  return 1.f / (1.f + __expf(-x));
}
// NaN-safe fast tanh: 1 - 2/(e^{2x}+1)
__device__ __forceinline__ float tanh_f(float x) {
  float e = __expf(2.f * x);
  return 1.f - 2.f / (e + 1.f);
}

// ---------- cast+relayout primitive: one wave converts a 16row x 32col f32
// region to slot-major bf16 (region image: elem = s4*128 + r16*8 + e).
// Coalesced global reads, transpose via +1-padded LDS, contiguous 16B writes.
__device__ __forceinline__ void relayout_region(
    const float* __restrict__ srcRowBase, size_t rowStride,
    unsigned short* __restrict__ dst, float* __restrict__ lp, int lane) {
  {
    int r = lane >> 2, c = (lane & 3) << 3;
    const float* s = srcRowBase + (size_t)r * rowStride + c;
    f32x4 a = *(const f32x4*)(s);
    f32x4 b = *(const f32x4*)(s + 4);
#pragma unroll
    for (int j = 0; j < 4; ++j) { lp[r * 33 + c + j] = a[j]; lp[r * 33 + c + 4 + j] = b[j]; }
  }
  int s4 = lane >> 4, r16 = lane & 15;
  us8 o;
#pragma unroll
  for (int j = 0; j < 8; ++j) o[j] = f2bf(lp[r16 * 33 + s4 * 8 + j]);
  *(us8*)(dst + lane * 8) = o;
}

// ---------- ONE merged prep kernel: all relayouts in a single launch ----------
__global__ __launch_bounds__(256) void prep_all(
    const float* __restrict__ inp, const float* __restrict__ hidden,
    const float* __restrict__ w_ih, const float* __restrict__ w_hh,
    const float* __restrict__ w_out,
    unsigned short* __restrict__ inp_r, unsigned short* __restrict__ h_r,
    unsigned short* __restrict__ wih_r, unsigned short* __restrict__ whh_r,
    unsigned short* __restrict__ wout_r)
{
  __shared__ float lp[4][16 * 33];
  const int wIn = threadIdx.x >> 6, lane = threadIdx.x & 63;
  const int gw  = blockIdx.x * 4 + wIn;

  const float* src; unsigned short* dst; int K, local, isA;
  if      (gw < 2048) { src = inp;    dst = inp_r;  K = 512;  isA = 1; local = gw; }
  else if (gw < 6144) { src = hidden; dst = h_r;    K = 1024; isA = 1; local = gw - 2048; }
  else if (gw < 6912) { src = w_ih;   dst = wih_r;  K = 512;  isA = 0; local = gw - 6144; }
  else if (gw < 8448) { src = w_hh;   dst = whh_r;  K = 1024; isA = 0; local = gw - 6912; }
  else                { src = w_out;  dst = wout_r; K = 1024; isA = 1; local = gw - 8448; }
  const int nkt = K >> 5;

  if (isA) {
    int p = local / nkt, kt = local - p * nkt;
    const float* base = src + (size_t)p * 128 * K + kt * 32;
    unsigned short* d = dst + (size_t)local * 4096;
#pragma unroll
    for (int g = 0; g < 8; ++g)
      relayout_region(base + (size_t)g * 16 * K, K, d + g * 512, lp[wIn], lane);
  } else {
    int qg = local / nkt, kt = local - qg * nkt;
    int q = qg / 3, g = qg - q * 3;
    const float* base = src + ((size_t)g * 1024 + q * 64) * K + kt * 32;
    unsigned short* d = dst + (size_t)local * 2048;
#pragma unroll
    for (int rg = 0; rg < 4; ++rg)
      relayout_region(base + (size_t)rg * 16 * K, K, d + rg * 512, lp[wIn], lane);
  }
}

#define GLOAD(gp, lp) __builtin_amdgcn_global_load_lds( \
    (const __attribute__((address_space(1))) unsigned int*)(gp), \
    (__attribute__((address_space(3))) unsigned int*)(lp), 16, 0, 0)

// ---------- Fused GRU cell: r14 best config. Static 4-buffer rotation,
// depth-2 prefetch, one barrier pair per step, counted vmcnt(10), setprio,
// concurrency-preserving XCD swizzle, direct epilogue stores. ----------
__global__ __launch_bounds__(256, 2) void fused_gru(
    const unsigned short* __restrict__ inp_r,
    const unsigned short* __restrict__ h_r,
    const unsigned short* __restrict__ wih_r,
    const unsigned short* __restrict__ whh_r,
    const float* __restrict__ b_ih,
    const float* __restrict__ b_hh,
    const float* __restrict__ hidden,      // [B,1024] f32
    float* __restrict__ hnew_f32,
    unsigned short* __restrict__ hnew_img)
{
  __shared__ unsigned short ls[4][10240];   // 4 x 20KB rotation

  const int tid  = threadIdx.x;
  const int lane = tid & 63;
  const int wave = tid >> 6;
  const int wr = wave >> 1, wc = wave & 1;

  const int f  = blockIdx.y * 16 + blockIdx.x;     // launch-order id
  const int bx = ((f & 7) << 1) | ((f >> 3) & 1);  // W-panel column 0..15
  const int by = f >> 4;                           // A row-panel 0..127

  f32x4 accR[4][2], accZ[4][2], accNi[4][2], accNh[4][2];
#pragma unroll
  for (int m = 0; m < 4; ++m)
#pragma unroll
    for (int n = 0; n < 2; ++n) {
      accR[m][n]  = f32x4{0.f, 0.f, 0.f, 0.f};
      accZ[m][n]  = f32x4{0.f, 0.f, 0.f, 0.f};
      accNi[m][n] = f32x4{0.f, 0.f, 0.f, 0.f};
      accNh[m][n] = f32x4{0.f, 0.f, 0.f, 0.f};
    }

  const int t4   = lane >> 4;                // k-octet 0..3
  const int l15  = lane & 15;
  const int rofs = t4 * 128 + l15 * 8;       // within-region read offset (elems)

  // induction staging pointers (wave-uniform; advance per step)
  const unsigned short* aptr = inp_r + (size_t)by * (16 * 4096);
  const unsigned short* wptr = wih_r + (size_t)bx * (3 * 16 * 2048);
  int wgs = 16 * 2048;                       // gate stride (elems)

#define STAGE(BUF) do { \
    GLOAD(aptr + tid * 8,           &ls[BUF][tid * 8]); \
    GLOAD(aptr + 2048 + tid * 8,    &ls[BUF][2048 + tid * 8]); \
    GLOAD(wptr + tid * 8,           &ls[BUF][4096 + tid * 8]); \
    GLOAD(wptr + wgs + tid * 8,     &ls[BUF][6144 + tid * 8]); \
    GLOAD(wptr + 2 * wgs + tid * 8, &ls[BUF][8192 + tid * 8]); \
    aptr += 4096; wptr += 2048; \
  } while (0)

#define COMPUTE(BUF, ACCN) do { \
    const unsigned short* lb = &ls[BUF][0]; \
    bf16x8 af[4], bfr[3][2]; \
    _Pragma("unroll") for (int m = 0; m < 4; ++m) \
      af[m] = *(const bf16x8*)&lb[(wr * 4 + m) * 512 + rofs]; \
    _Pragma("unroll") for (int g = 0; g < 3; ++g) { \
      _Pragma("unroll") for (int n = 0; n < 2; ++n) \
        bfr[g][n] = *(const bf16x8*)&lb[4096 + g * 2048 + (wc * 2 + n) * 512 + rofs]; \
    } \
    __builtin_amdgcn_s_setprio(1); \
    _Pragma("unroll") for (int m = 0; m < 4; ++m) { \
      _Pragma("unroll") for (int n = 0; n < 2; ++n) { \
        accR[m][n] = __builtin_amdgcn_mfma_f32_16x16x32_bf16(af[m], bfr[0][n], accR[m][n], 0, 0, 0); \
        accZ[m][n] = __builtin_amdgcn_mfma_f32_16x16x32_bf16(af[m], bfr[1][n], accZ[m][n], 0, 0, 0); \
        ACCN[m][n] = __builtin_amdgcn_mfma_f32_16x16x32_bf16(af[m], bfr[2][n], ACCN[m][n], 0, 0, 0); \
      } \
    } \
    __builtin_amdgcn_s_setprio(0); \
  } while (0)

#define WAIT10 asm volatile("s_waitcnt vmcnt(10)" ::: "memory")
#define BARR   __builtin_amdgcn_s_barrier()
#define STEP(SB, CB, ACCN) do { STAGE(SB); WAIT10; BARR; COMPUTE(CB, ACCN); } while (0)

  // 48 kt32 tiles: 0..15 inp/wih -> accNi, 16..47 h/whh -> accNh
  STAGE(0); STAGE(1);                        // tiles 0,1
#pragma unroll 1
  for (int i = 0; i < 3; ++i) {              // t = 0..11, stage 2..13
    STEP(2, 0, accNi); STEP(3, 1, accNi); STEP(0, 2, accNi); STEP(1, 3, accNi);
  }
  STEP(2, 0, accNi);                         // t=12, stage 14
  STEP(3, 1, accNi);                         // t=13, stage 15
  aptr = h_r + (size_t)by * (32 * 4096);     // switch to h-phase
  wptr = whh_r + (size_t)bx * (3 * 32 * 2048);
  wgs = 32 * 2048;
  STEP(0, 2, accNi);                         // t=14, stage 16
  STEP(1, 3, accNi);                         // t=15, stage 17
#pragma unroll 1
  for (int i = 0; i < 7; ++i) {              // t = 16..43, stage 18..45
    STEP(2, 0, accNh); STEP(3, 1, accNh); STEP(0, 2, accNh); STEP(1, 3, accNh);
  }
  STEP(2, 0, accNh);                         // t=44, stage 46
  STEP(3, 1, accNh);                         // t=45, stage 47
  asm volatile("s_waitcnt vmcnt(5)" ::: "memory"); BARR;
  COMPUTE(2, accNh);                         // t=46
  asm volatile("s_waitcnt vmcnt(0)" ::: "memory"); BARR;
  COMPUTE(3, accNh);                         // t=47

#undef STAGE
#undef COMPUTE
#undef WAIT10
#undef BARR
#undef STEP

  // ---- epilogue: gate math + blend ----
  // C/D layout: col = lane&15, row = (lane>>4)*4 + r
  const int m0 = by * 128;
  const int n0 = bx * 64;
  const int colb = n0 + wc * 32 + l15;
  const int rowb = m0 + wr * 64 + (t4 << 2);
#pragma unroll
  for (int n = 0; n < 2; ++n) {
    int c = colb + n * 16;
    float br  = b_ih[c]        + b_hh[c];
    float bz  = b_ih[1024 + c] + b_hh[1024 + c];
    float bni = b_ih[2048 + c];
    float bnh = b_hh[2048 + c];
    const int kt = c >> 5;                 // image k-chunk
    const int s  = (c >> 3) & 3;           // k-octet slot
    const int e  = c & 7;
#pragma unroll
    for (int m = 0; m < 4; ++m) {
      int row = rowb + m * 16;
#pragma unroll
      for (int r = 0; r < 4; ++r) {
        float rg = sigmoid_f(accR[m][n][r] + br);
        float zg = sigmoid_f(accZ[m][n][r] + bz);
        float ng = tanh_f((accNi[m][n][r] + bni) + rg * (accNh[m][n][r] + bnh));
        int rw = row + r;
        float ho = hidden[(size_t)rw * 1024 + c];
        float hv = (1.f - zg) * ng + zg * ho;
        hnew_f32[(size_t)rw * 1024 + c] = hv;
        // slot-major GEMM A-image: tile (p*32+kt), region (row>>4)&7
        size_t img = ((size_t)((rw >> 7) * 32 + kt)) * 4096
                   + (((rw >> 4) & 7) * 512) + s * 128 + (rw & 15) * 8 + e;
        hnew_img[img] = f2bf(hv);
      }
    }
  }
}

// ---------- out GEMM: r12 structure (16x16x32, 4-buffer rotation). ----------
__global__ __launch_bounds__(256, 2) void gemm_out(
    const unsigned short* __restrict__ A_img,   // [128 p-tiles][32 kt][4096]
    const unsigned short* __restrict__ B_img,   // [4 p-tiles][32 kt][4096]
    float* __restrict__ Cout,
    const float* __restrict__ bias)
{
  __shared__ unsigned short ls[4][8192];   // 4 x 16KB rotation (A 4096 | B 4096)

  const int tid  = threadIdx.x;
  const int lane = tid & 63;
  const int wave = tid >> 6;
  const int wr = wave >> 1, wc = wave & 1;

  f32x4 acc[4][4];
#pragma unroll
  for (int i = 0; i < 4; ++i)
#pragma unroll
    for (int j = 0; j < 4; ++j) acc[i][j] = f32x4{0.f, 0.f, 0.f, 0.f};

  const int t4   = lane >> 4;
  const int l15  = lane & 15;
  const int rofs = t4 * 128 + l15 * 8;

  const unsigned short* aptr = A_img + (size_t)blockIdx.y * (32 * 4096);
  const unsigned short* bptr = B_img + (size_t)blockIdx.x * (32 * 4096);

#define STAGE(BUF) do { \
    GLOAD(aptr + tid * 8,        &ls[BUF][tid * 8]); \
    GLOAD(aptr + 2048 + tid * 8, &ls[BUF][2048 + tid * 8]); \
    GLOAD(bptr + tid * 8,        &ls[BUF][4096 + tid * 8]); \
    GLOAD(bptr + 2048 + tid * 8, &ls[BUF][6144 + tid * 8]); \
    aptr += 4096; bptr += 4096; \
  } while (0)

#define COMPUTE(BUF) do { \
    const unsigned short* lb = &ls[BUF][0]; \
    bf16x8 af[4], bfr[4]; \
    _Pragma("unroll") for (int m = 0; m < 4; ++m) \
      af[m] = *(const bf16x8*)&lb[(wr * 4 + m) * 512 + rofs]; \
    _Pragma("unroll") for (int n = 0; n < 4; ++n) \
      bfr[n] = *(const bf16x8*)&lb[4096 + (wc * 4 + n) * 512 + rofs]; \
    __builtin_amdgcn_s_setprio(1); \
    _Pragma("unroll") for (int m = 0; m < 4; ++m) { \
      _Pragma("unroll") for (int n = 0; n < 4; ++n) \
        acc[m][n] = __builtin_amdgcn_mfma_f32_16x16x32_bf16(af[m], bfr[n], acc[m][n], 0, 0, 0); \
    } \
    __builtin_amdgcn_s_setprio(0); \
  } while (0)

#define WAIT8 asm volatile("s_waitcnt vmcnt(8)" ::: "memory")
#define BARR  __builtin_amdgcn_s_barrier()
#define STEP(SB, CB) do { STAGE(SB); WAIT8; BARR; COMPUTE(CB); } while (0)

  STAGE(0); STAGE(1);
#pragma unroll 1
  for (int i = 0; i < 7; ++i) {              // t = 0..27, stage 2..29
    STEP(2, 0); STEP(3, 1); STEP(0, 2); STEP(1, 3);
  }
  STEP(2, 0);                                // t=28, stage 30
  STEP(3, 1);                                // t=29, stage 31
  asm volatile("s_waitcnt vmcnt(4)" ::: "memory"); BARR;
  COMPUTE(2);                                // t=30
  asm volatile("s_waitcnt vmcnt(0)" ::: "memory"); BARR;
  COMPUTE(3);                                // t=31

#undef STAGE
#undef COMPUTE
#undef WAIT8
#undef BARR
#undef STEP

  const int m0 = blockIdx.y * 128;
  const int n0 = blockIdx.x * 128;
  const int colb = n0 + wc * 64 + l15;
  const int rowb = m0 + wr * 64 + (t4 << 2);
#pragma unroll
  for (int n = 0; n < 4; ++n) {
    int col = colb + n * 16;
    float bv = bias[col];
#pragma unroll
    for (int m = 0; m < 4; ++m) {
      int row = rowb + m * 16;
#pragma unroll
      for (int r = 0; r < 4; ++r) {
        Cout[(size_t)(row + r) * 512 + col] = tanh_f(acc[m][n][r] + bv);
      }
    }
  }
}

// ---------- launch ----------
extern "C" void kernel_launch(void* const* d_in, const int* in_sizes, int n_in,
                              void* d_out, int out_size, void* d_ws, size_t ws_size,
                              hipStream_t stream) {
  const int B = 16384, H = 1024, O = 512;
  const float* inp    = (const float*)d_in[0];
  const float* hidden = (const float*)d_in[1];
  const float* w_ih   = (const float*)d_in[2];
  const float* w_hh   = (const float*)d_in[3];
  const float* b_ih   = (const float*)d_in[4];
  const float* b_hh   = (const float*)d_in[5];
  const float* w_out  = (const float*)d_in[6];
  const float* b_out  = (const float*)d_in[7];

  float* out      = (float*)d_out;                     // [B, O] f32
  float* hnew_out = out + (size_t)B * O;               // [1, B, H] f32

  char* ws = (char*)d_ws;
  size_t need = 0;
  auto carve = [&](size_t elems) {
    unsigned short* p = (unsigned short*)(ws + need);
    need += elems * 2;
    return p;
  };
  unsigned short* inp_r  = carve((size_t)B * O);       // 16 MB (image)
  unsigned short* h_r    = carve((size_t)B * H);       // 32 MB (image)
  unsigned short* wih_r  = carve((size_t)3 * H * O);   // 3 MB (image)
  unsigned short* whh_r  = carve((size_t)3 * H * H);   // 6 MB (image)
  unsigned short* wout_r = carve((size_t)O * H);       // 1 MB (image)
  unsigned short* hnew_i = carve((size_t)B * H);       // 32 MB (image)
  if (ws_size < need) return;

  // one merged prep launch: 8576 waves -> 2144 blocks
  prep_all<<<dim3(2144), dim3(256), 0, stream>>>(
      inp, hidden, w_ih, w_hh, w_out, inp_r, h_r, wih_r, whh_r, wout_r);

  // fused GRU cell -> h_new (f32 into d_out tail, bf16 image into ws)
  fused_gru<<<dim3(16, 128), dim3(256), 0, stream>>>(
      inp_r, h_r, wih_r, whh_r, b_ih, b_hh, hidden, hnew_out, hnew_i);

  // out = tanh(h_new @ w_out^T + b_out)
  gemm_out<<<dim3(O / 128, B / 128), dim3(256), 0, stream>>>(
      hnew_i, wout_r, out, b_out);
}